// Round 9
// baseline (264.478 us; speedup 1.0000x reference)
//
#include <hip/hip_runtime.h>

#define B_   8
#define C_   256
#define TC_  512
#define HW_  2304   // 48*48
#define EPS_ 1e-6f
#define JS_  8      // column splits
#define TPS_ 9      // tiles (of 32 cols) per split: 72/8

typedef __bf16 bf16_t;
typedef __bf16 bf16x8 __attribute__((ext_vector_type(8)));
typedef __bf16 bf16x4_t __attribute__((ext_vector_type(4)));
typedef float  f32x4 __attribute__((ext_vector_type(4)));
typedef unsigned int  u32;
typedef unsigned int  u32x4 __attribute__((ext_vector_type(4)));
typedef long long     i64;
typedef unsigned char u8;

// async 16B global->LDS; lds dest is wave-uniform base (lane i -> base+16i)
__device__ __forceinline__ void g2l16(const void* g, void* l) {
    __builtin_amdgcn_global_load_lds(
        (const __attribute__((address_space(1))) unsigned int*)g,
        (__attribute__((address_space(3))) unsigned int*)l, 16, 0, 0);
}

__device__ __forceinline__ u8 to_fp8(float v) {
    return (u8)(__builtin_amdgcn_cvt_pk_fp8_f32(v, v, 0, false) & 0xff);
}

// ---------------------------------------------------------------------------
// W -> fragment-major bf16 (unchanged from round 8).
// ---------------------------------------------------------------------------
__global__ __launch_bounds__(256)
void wfrag_kernel(const float* __restrict__ wq, const float* __restrict__ wk,
                  const float* __restrict__ wv,
                  bf16_t* __restrict__ oq, bf16_t* __restrict__ ok,
                  bf16_t* __restrict__ ov)
{
    const int fid = blockIdx.x * 4 + (threadIdx.x >> 6);   // 0..639
    const int lane = threadIdx.x & 63;
    const int l16 = lane & 15, quad = lane >> 4;

    const float* src; bf16_t* dst; int cin, f;
    if (fid < 128)      { src = wq; dst = oq; cin = C_;  f = fid; }
    else if (fid < 384) { src = wk; dst = ok; cin = TC_; f = fid - 128; }
    else                { src = wv; dst = ov; cin = TC_; f = fid - 384; }
    const int nks = cin / 32;
    const int ot = f / nks, ks = f % nks;

    const float* s = src + (size_t)(ot * 16 + l16) * cin + ks * 32 + quad * 8;
    float4 a = *(const float4*)(s);
    float4 b = *(const float4*)(s + 4);
    bf16x8 o;
    o[0] = (__bf16)a.x; o[1] = (__bf16)a.y; o[2] = (__bf16)a.z; o[3] = (__bf16)a.w;
    o[4] = (__bf16)b.x; o[5] = (__bf16)b.y; o[6] = (__bf16)b.z; o[7] = (__bf16)b.w;
    *(bf16x8*)(dst + (size_t)f * 512 + lane * 8) = o;
}

// ---------------------------------------------------------------------------
// Fused 1x1-conv stage (unchanged from round 8).
// ---------------------------------------------------------------------------
template<int CIN, bool DO_V>
__global__ __launch_bounds__(256, 4)
void convqkv_kernel(const float* __restrict__ X, const bf16_t* __restrict__ Wa,
                    const bf16_t* __restrict__ Wvp, u8* __restrict__ outA,
                    u8* __restrict__ outV)
{
    const int bid = blockIdx.x;
    const int b  = bid & 7;
    const int n0 = (bid >> 3) * 16;
    const int tid = threadIdx.x;
    const int wv = tid >> 6;
    const int lane = tid & 63;
    const int quad = lane >> 4, l16 = lane & 15;
    const int NKS = CIN / 32;

    __shared__ bf16_t T[16][CIN + 8];
    __shared__ float ssp[4][16];

    {
        const float* Xb = X + (size_t)b * CIN * HW_ + n0;
        const int cl = tid >> 2;
        const int n4 = (tid & 3) * 4;
#pragma unroll
        for (int cp = 0; cp < CIN; cp += 64) {
            float4 v = *(const float4*)(Xb + (size_t)(cp + cl) * HW_ + n4);
            T[n4 + 0][cp + cl] = (__bf16)v.x;
            T[n4 + 1][cp + cl] = (__bf16)v.y;
            T[n4 + 2][cp + cl] = (__bf16)v.z;
            T[n4 + 3][cp + cl] = (__bf16)v.w;
        }
    }
    __syncthreads();

    bf16x8 af[CIN / 32];
#pragma unroll
    for (int ks = 0; ks < CIN / 32; ks++)
        af[ks] = *(const bf16x8*)(&T[l16][ks * 32 + quad * 8]);

    const int ot0 = wv * 4;

    f32x4 accK[4];
#pragma unroll
    for (int p = 0; p < 4; p++) accK[p] = (f32x4){0.f, 0.f, 0.f, 0.f};
    {
        const bf16_t* wbase = Wa + ((size_t)ot0 * NKS) * 512 + lane * 8;
#pragma unroll
        for (int ks = 0; ks < CIN / 32; ks++)
#pragma unroll
            for (int p = 0; p < 4; p++) {
                bf16x8 bw = *(const bf16x8*)(wbase + (size_t)(p * NKS + ks) * 512);
                accK[p] = __builtin_amdgcn_mfma_f32_16x16x32_bf16(af[ks], bw, accK[p], 0, 0, 0);
            }
    }

    {
        float ssr[4];
#pragma unroll
        for (int r = 0; r < 4; r++) {
            float ss = accK[0][r] * accK[0][r] + accK[1][r] * accK[1][r]
                     + accK[2][r] * accK[2][r] + accK[3][r] * accK[3][r];
            ss += __shfl_xor(ss, 1);
            ss += __shfl_xor(ss, 2);
            ss += __shfl_xor(ss, 4);
            ss += __shfl_xor(ss, 8);
            ssr[r] = ss;
        }
        if (l16 == 0) {
#pragma unroll
            for (int r = 0; r < 4; r++) ssp[wv][quad * 4 + r] = ssr[r];
        }
    }

    f32x4 accV[4];
    if (DO_V) {
#pragma unroll
        for (int p = 0; p < 4; p++) accV[p] = (f32x4){0.f, 0.f, 0.f, 0.f};
        const bf16_t* wbase = Wvp + ((size_t)ot0 * NKS) * 512 + lane * 8;
#pragma unroll
        for (int ks = 0; ks < CIN / 32; ks++)
#pragma unroll
            for (int p = 0; p < 4; p++) {
                bf16x8 aw = *(const bf16x8*)(wbase + (size_t)(p * NKS + ks) * 512);
                accV[p] = __builtin_amdgcn_mfma_f32_16x16x32_bf16(aw, af[ks], accV[p], 0, 0, 0);
            }
    }

    __syncthreads();

    float scale[4];
#pragma unroll
    for (int r = 0; r < 4; r++) {
        int px = quad * 4 + r;
        float s = ssp[0][px] + ssp[1][px] + ssp[2][px] + ssp[3][px];
        scale[r] = 1.0f / fmaxf(sqrtf(s), EPS_);
    }
    {
        u8* oa = outA + ((size_t)b * HW_ + n0 + quad * 4) * C_ + l16;
#pragma unroll
        for (int p = 0; p < 4; p++)
#pragma unroll
            for (int r = 0; r < 4; r++)
                oa[(size_t)r * C_ + (ot0 + p) * 16] = to_fp8(accK[p][r] * scale[r]);
    }

    if (DO_V) {
#pragma unroll
        for (int p = 0; p < 4; p++)
#pragma unroll
            for (int r = 0; r < 4; r++)
                outV[((size_t)b * C_ + (ot0 + p) * 16 + quad * 4 + r) * HW_ + n0 + l16]
                    = to_fp8(accV[p][r]);
    }
}

// ---------------------------------------------------------------------------
// Attention partials, whole-split LDS residency.
// Block: 128 Q-rows x 288-col split.  LDS: Kslab 72K + Vslab 72K + Psh 6K.
// One staging burst + barrier, then TPS_ tiles of pure LDS+MFMA compute
// (no global ops in the loop -> no vmcnt drain on the 2 barriers/tile).
// QK phase: wave wv computes m-tiles {2wv, 2wv+1} (rows row0..row0+31),
//   writes P (fp8, col-interleaved) to shared Psh.
// PV phase: wave wv owns c-quarter [wv*64, wv*64+64): reads all 8 m-tiles'
//   P frags, 4 V frags (each reused x8 m-tiles) -> O[8][4] f32x4 (128 VGPR,
//   fine at 1 block/CU -> 1 wave/SIMD -> 256-VGPR budget).
// ---------------------------------------------------------------------------
__global__ __launch_bounds__(256, 1)
void attn_part_kernel(const u8* __restrict__ q8, const u8* __restrict__ k8,
                      const u8* __restrict__ v8,
                      bf16_t* __restrict__ Opart, float* __restrict__ lpart)
{
    const int bid = blockIdx.x;
    const int b   = bid & 7;              // XCD affinity
    const int rr  = bid >> 3;
    const int js  = rr % JS_;
    const int mtb = rr / JS_;             // 0..17
    const int wv   = threadIdx.x >> 6;
    const int lane = threadIdx.x & 63;
    const int quad = lane >> 4;
    const int l16  = lane & 15;
    const int row0 = mtb * 128 + wv * 32;       // QK-phase rows of this wave
    const int jbase = js * (TPS_ * 32);

    const u8* qb = q8 + (size_t)b * HW_ * C_;
    const u8* kb = k8 + (size_t)b * HW_ * C_;
    const u8* vb = v8 + (size_t)b * C_ * HW_;

    __shared__ u8 Kslab[TPS_ * 8192];   // [tt][s 0..15][j 0..31][16B]
    __shared__ u8 Vslab[TPS_ * 8192];   // [tt][c 0..255][32B]
    __shared__ u8 Psh[8 * 768];         // [mt][row 16 x 48B interleaved fp8]

    // ---- stage the whole split: 36 g2l16 per wave ----
    const int kj = lane & 31, kh = lane >> 5;
    const int vg = lane & 1,  vc = lane >> 1;
    for (int t = 0; t < 18; t++) {
        int ii = wv * 18 + t;                   // 0..71
        int tt = ii >> 3, i = ii & 7;
        g2l16(kb + (size_t)(jbase + tt * 32 + kj) * C_ + (i * 2 + kh) * 16,
              Kslab + ii * 1024);
    }
    for (int t = 0; t < 18; t++) {
        int jj = wv * 18 + t;
        int tt = jj >> 3, i2 = jj & 7;
        g2l16(vb + (size_t)(i2 * 32 + vc) * HW_ + jbase + tt * 32 + vg * 16,
              Vslab + jj * 1024);
    }

    // ---- Q fragments (global, overlaps staging) ----
    i64 aq0[8], aq1[8];
    {
        const u8* r0 = qb + (size_t)(row0 + l16) * C_ + quad * 8;
        const u8* r1 = r0 + 16 * C_;
#pragma unroll
        for (int t = 0; t < 8; t++) {
            aq0[t] = *(const i64*)(r0 + t * 32);
            aq1[t] = *(const i64*)(r1 + t * 32);
        }
    }

    f32x4 O[8][4];
#pragma unroll
    for (int m = 0; m < 8; m++)
#pragma unroll
        for (int c = 0; c < 4; c++) O[m][c] = (f32x4){0.f, 0.f, 0.f, 0.f};
    float lsum0[4] = {0.f, 0.f, 0.f, 0.f};
    float lsum1[4] = {0.f, 0.f, 0.f, 0.f};

    __syncthreads();   // slabs resident (the only vmcnt-draining barrier)

    u8* pw = Psh + wv * 1536;
    const int koff = (quad >> 1) * 512 + l16 * 16 + (quad & 1) * 8;
    const u32 sel = (quad < 2) ? 0x06040200u : 0x07050301u;
    const int vcol = (wv * 64 + l16) * 32 + quad * 8;

    for (int tt = 0; tt < TPS_; tt++) {
        const u8* Kb = Kslab + tt * 8192;
        const u8* Vb = Vslab + tt * 8192;

        // ---- QK^T for this wave's 2 m-tiles ----
        f32x4 s00 = (f32x4){0.f,0.f,0.f,0.f}, s01 = (f32x4){0.f,0.f,0.f,0.f};
        f32x4 s10 = (f32x4){0.f,0.f,0.f,0.f}, s11 = (f32x4){0.f,0.f,0.f,0.f};
#pragma unroll
        for (int t = 0; t < 8; t++) {
            i64 bk0 = *(const i64*)(Kb + t * 1024 + koff);
            i64 bk1 = *(const i64*)(Kb + t * 1024 + koff + 256);
            s00 = __builtin_amdgcn_mfma_f32_16x16x32_fp8_fp8(aq0[t], bk0, s00, 0, 0, 0);
            s01 = __builtin_amdgcn_mfma_f32_16x16x32_fp8_fp8(aq0[t], bk1, s01, 0, 0, 0);
            s10 = __builtin_amdgcn_mfma_f32_16x16x32_fp8_fp8(aq1[t], bk0, s10, 0, 0, 0);
            s11 = __builtin_amdgcn_mfma_f32_16x16x32_fp8_fp8(aq1[t], bk1, s11, 0, 0, 0);
        }
        // ---- exp, lsum, P (fp8 interleaved) -> shared LDS ----
#pragma unroll
        for (int r = 0; r < 4; r++) {
            float p00 = __expf(s00[r] * 0.0625f), p01 = __expf(s01[r] * 0.0625f);
            float p10 = __expf(s10[r] * 0.0625f), p11 = __expf(s11[r] * 0.0625f);
            lsum0[r] += p00 + p01;
            lsum1[r] += p10 + p11;
            u32 w0 = __builtin_amdgcn_cvt_pk_fp8_f32(p00, p01, 0, false);
            u32 w1 = __builtin_amdgcn_cvt_pk_fp8_f32(p10, p11, 0, false);
            int ro = (quad * 4 + r) * 48 + l16 * 2;
            *(short*)(pw + ro)       = (short)w0;
            *(short*)(pw + 768 + ro) = (short)w1;
        }
        __syncthreads();   // P complete (no pending global ops)

        // ---- PV: all 8 m-tiles x this wave's 4 c-tiles ----
        i64 ap[8];
#pragma unroll
        for (int mt = 0; mt < 8; mt++) {
            u32x4 d = *(const u32x4*)(Psh + mt * 768 + l16 * 48 + (quad & 1) * 16);
            u32 lo = __builtin_amdgcn_perm(d[1], d[0], sel);
            u32 hi = __builtin_amdgcn_perm(d[3], d[2], sel);
            ap[mt] = ((i64)hi << 32) | (i64)lo;
        }
        i64 bv[4];
#pragma unroll
        for (int ct = 0; ct < 4; ct++)
            bv[ct] = *(const i64*)(Vb + vcol + ct * 512);
#pragma unroll
        for (int mt = 0; mt < 8; mt++)
#pragma unroll
            for (int ct = 0; ct < 4; ct++)
                O[mt][ct] = __builtin_amdgcn_mfma_f32_16x16x32_fp8_fp8(ap[mt], bv[ct], O[mt][ct], 0, 0, 0);
        __syncthreads();   // P consumed; next tile may overwrite
    }

    // ---- lsum reduction + store (QK-phase rows) ----
#pragma unroll
    for (int r = 0; r < 4; r++) {
        float t0 = lsum0[r], t1 = lsum1[r];
        t0 += __shfl_xor(t0, 1); t0 += __shfl_xor(t0, 2);
        t0 += __shfl_xor(t0, 4); t0 += __shfl_xor(t0, 8);
        t1 += __shfl_xor(t1, 1); t1 += __shfl_xor(t1, 2);
        t1 += __shfl_xor(t1, 4); t1 += __shfl_xor(t1, 8);
        lsum0[r] = t0; lsum1[r] = t1;
    }
    float* lp = lpart + (size_t)(js * B_ + b) * HW_;
    if (l16 == 0) {
        float4 a0; a0.x = lsum0[0]; a0.y = lsum0[1]; a0.z = lsum0[2]; a0.w = lsum0[3];
        float4 a1; a1.x = lsum1[0]; a1.y = lsum1[1]; a1.z = lsum1[2]; a1.w = lsum1[3];
        *(float4*)(lp + row0 + quad * 4)      = a0;
        *(float4*)(lp + row0 + 16 + quad * 4) = a1;
    }

    // ---- O store: c-quarter x all 8 m-tiles ----
    bf16_t* op = Opart + (size_t)(js * B_ + b) * C_ * HW_;
#pragma unroll
    for (int mt = 0; mt < 8; mt++)
#pragma unroll
        for (int ct = 0; ct < 4; ct++) {
            int c = wv * 64 + ct * 16 + l16;
            bf16x4_t v0;
            v0[0] = (__bf16)O[mt][ct][0]; v0[1] = (__bf16)O[mt][ct][1];
            v0[2] = (__bf16)O[mt][ct][2]; v0[3] = (__bf16)O[mt][ct][3];
            *(bf16x4_t*)(op + (size_t)c * HW_ + mtb * 128 + mt * 16 + quad * 4) = v0;
        }
}

// ---------------------------------------------------------------------------
// out[b][c][n] = x + alpha * (sum_js Opart) / (sum_js lpart[b][n])
// ---------------------------------------------------------------------------
__global__ __launch_bounds__(256)
void epilogue_kernel(const float* __restrict__ x, const bf16_t* __restrict__ Opart,
                     const float* __restrict__ lpart, const float* __restrict__ alphaPtr,
                     float* __restrict__ out, int JS)
{
    const float a = *alphaPtr;
    const size_t S = (size_t)B_ * C_ * HW_;
    size_t flat = ((size_t)blockIdx.x * 256 + threadIdx.x) * 4;
    int bc = (int)(flat / HW_);
    int n  = (int)(flat % HW_);
    int b  = bc >> 8;
    float4 xv = *(const float4*)(x + flat);
    float s0 = 0.f, s1 = 0.f, s2 = 0.f, s3 = 0.f;
    float l0 = 0.f, l1 = 0.f, l2 = 0.f, l3 = 0.f;
    for (int js = 0; js < JS; js++) {
        bf16x4_t ov = *(const bf16x4_t*)(Opart + (size_t)js * S + flat);
        s0 += (float)ov[0]; s1 += (float)ov[1];
        s2 += (float)ov[2]; s3 += (float)ov[3];
        float4 lv = *(const float4*)(lpart + (size_t)(js * B_ + b) * HW_ + n);
        l0 += lv.x; l1 += lv.y; l2 += lv.z; l3 += lv.w;
    }
    float4 r;
    r.x = xv.x + a * s0 / l0;
    r.y = xv.y + a * s1 / l1;
    r.z = xv.z + a * s2 / l2;
    r.w = xv.w + a * s3 / l3;
    *(float4*)(out + flat) = r;
}

// ---------------------------------------------------------------------------
extern "C" void kernel_launch(void* const* d_in, const int* in_sizes, int n_in,
                              void* d_out, int out_size, void* d_ws, size_t ws_size,
                              hipStream_t stream)
{
    (void)in_sizes; (void)n_in; (void)out_size; (void)ws_size;
    const float* x     = (const float*)d_in[0];
    const float* token = (const float*)d_in[1];
    const float* Wq    = (const float*)d_in[2];
    const float* Wk    = (const float*)d_in[3];
    const float* Wv    = (const float*)d_in[4];
    const float* alpha = (const float*)d_in[5];
    float* out = (float*)d_out;

    const size_t S = (size_t)B_ * HW_ * C_;   // 4,718,592 elements

    char* ws = (char*)d_ws;
    bf16_t* WqL   = (bf16_t*)(ws + 6 * S);       // frag-major, 128 KB
    bf16_t* WkL   = WqL + (size_t)C_ * C_;       // frag-major, 256 KB
    bf16_t* WvL   = WkL + (size_t)C_ * TC_;      // frag-major, 256 KB
    u8*     q8    = (u8*)(ws + 7 * S);           // fp8 [b][n][C]
    u8*     k8    = (u8*)(ws + 8 * S);           // fp8 [b][n][C]
    u8*     v8    = (u8*)(ws + 9 * S);           // fp8 [b][C][n]
    bf16_t* Opart = (bf16_t*)(ws + 12 * S);      // [js][b][c][n] bf16
    float*  lpart = (float*)(ws + (12 + 2 * (size_t)JS_) * S);

    wfrag_kernel<<<dim3(160), dim3(256), 0, stream>>>(Wq, Wk, Wv, WqL, WkL, WvL);
    convqkv_kernel<C_,  false><<<dim3(B_ * HW_ / 16), dim3(256), 0, stream>>>(x,     WqL, nullptr, q8, nullptr);
    convqkv_kernel<TC_, true ><<<dim3(B_ * HW_ / 16), dim3(256), 0, stream>>>(token, WkL, WvL,     k8, v8);
    attn_part_kernel<<<dim3(JS_ * B_ * (HW_ / 128)), dim3(256), 0, stream>>>(q8, k8, v8, Opart, lpart);
    epilogue_kernel<<<dim3((int)(S / 1024)), dim3(256), 0, stream>>>(x, Opart, lpart, alpha, out, JS_);
}